// Round 6
// baseline (758.380 us; speedup 1.0000x reference)
//
#include <hip/hip_runtime.h>
#include <hip/hip_bf16.h>

// Problem constants
#define Bb 8
#define Tt 4
#define Nn 1024
#define Mm 4096
#define BT 32         // B*T
#define CIN 256
#define CORIG 128
#define CTOT 384      // CIN + CORIG
#define P1 256
#define P2 256
#define EPS_D 1e-8f
#define EPS_BN 1e-5f

typedef __attribute__((ext_vector_type(4))) float f32x4;
typedef __attribute__((ext_vector_type(8))) short s16x8;

// ---- bf16 split helpers (RTNE; fp32-grade when both pieces used) ----
__device__ __forceinline__ unsigned short f2bf(float f) {
    unsigned int u = __float_as_uint(f);
    unsigned int r = (u + 0x7FFFu + ((u >> 16) & 1u)) >> 16;
    return (unsigned short)r;
}
__device__ __forceinline__ float bf2f(unsigned short b) {
    return __uint_as_float((unsigned int)b << 16);
}
__device__ __forceinline__ void split_bf16(float f, unsigned short& h, unsigned short& l) {
    h = f2bf(f);
    l = f2bf(f - bf2f(h));
}
__device__ __forceinline__ unsigned int pack_bf(float f) {
    unsigned short h, l;
    split_bf16(f, h, l);
    return ((unsigned int)h << 16) | (unsigned int)l;
}

// ---------------------------------------------------------------------------
// Kernel 1: split W[o][k] fp32 -> bf16 hi/lo pair (same [o][k] layout)
// ---------------------------------------------------------------------------
__global__ __launch_bounds__(256) void prep_w_kernel(
    const float* __restrict__ W, unsigned short* __restrict__ hi,
    unsigned short* __restrict__ lo, int total)
{
    int i = blockIdx.x * 256 + threadIdx.x;
    if (i < total) {
        unsigned short h, l;
        split_bf16(W[i], h, l);
        hi[i] = h; lo[i] = l;
    }
}

// ---------------------------------------------------------------------------
// Kernel 1b: zero the BN-stat accumulators (ws is poisoned before each launch)
// ---------------------------------------------------------------------------
__global__ __launch_bounds__(256) void zero_stats_kernel(float* __restrict__ p)
{
    p[blockIdx.x * 256 + threadIdx.x] = 0.0f;
}

// ---------------------------------------------------------------------------
// Kernel 2: three_nn — per query point find 3 nearest (squared dist), weights
// ---------------------------------------------------------------------------
__global__ __launch_bounds__(256) void three_nn_kernel(
    const float* __restrict__ xyzs,   // [BT][N][3]
    const float* __restrict__ oxyzs,  // [BT][M][3]
    int*   __restrict__ idx_out,      // [BT][M][3]
    float* __restrict__ w_out)        // [BT][M][3]
{
    __shared__ float sx[Nn], sy[Nn], sz[Nn];
    int bt = blockIdx.y;
    const float* base = xyzs + (size_t)bt * Nn * 3;
    for (int i = threadIdx.x; i < Nn; i += 256) {
        sx[i] = base[i * 3 + 0];
        sy[i] = base[i * 3 + 1];
        sz[i] = base[i * 3 + 2];
    }
    __syncthreads();

    int m = blockIdx.x * 256 + threadIdx.x;
    size_t q = ((size_t)bt * Mm + m) * 3;
    float qx = oxyzs[q + 0], qy = oxyzs[q + 1], qz = oxyzs[q + 2];

    float d0 = 3.4e38f, d1 = 3.4e38f, d2v = 3.4e38f;
    int   i0 = 0, i1 = 0, i2 = 0;
    #pragma unroll 4
    for (int n = 0; n < Nn; n++) {
        float dx = qx - sx[n], dy = qy - sy[n], dz = qz - sz[n];
        float d = dx * dx + dy * dy + dz * dz;
        bool lt0 = d < d0, lt1 = d < d1, lt2 = d < d2v;
        i2  = lt1 ? i1 : (lt2 ? n : i2);
        d2v = lt1 ? d1 : (lt2 ? d : d2v);
        i1  = lt0 ? i0 : (lt1 ? n : i1);
        d1  = lt0 ? d0 : (lt1 ? d : d1);
        i0  = lt0 ? n : i0;
        d0  = lt0 ? d : d0;
    }
    float w0 = 1.0f / (d0 + EPS_D);
    float w1 = 1.0f / (d1 + EPS_D);
    float w2 = 1.0f / (d2v + EPS_D);
    float inv = 1.0f / (w0 + w1 + w2);
    idx_out[q + 0] = i0; idx_out[q + 1] = i1; idx_out[q + 2] = i2;
    w_out[q + 0] = w0 * inv; w_out[q + 1] = w1 * inv; w_out[q + 2] = w2 * inv;
}

// ---------------------------------------------------------------------------
// Kernel 3: transpose feats [BT][256][1024] -> featsT [BT][1024][256]
// ---------------------------------------------------------------------------
__global__ __launch_bounds__(256) void transpose_feats_kernel(
    const float* __restrict__ feats, float* __restrict__ featsT)
{
    __shared__ float tile[64][65];
    int bt = blockIdx.z;
    int n0 = blockIdx.x * 64;
    int c0 = blockIdx.y * 64;
    int tx = threadIdx.x & 63;
    int ty = threadIdx.x >> 6;
    const float* src = feats + ((size_t)bt * CIN + c0) * Nn + n0;
    #pragma unroll
    for (int r = 0; r < 16; r++) {
        int c = ty + r * 4;
        tile[c][tx] = src[(size_t)c * Nn + tx];
    }
    __syncthreads();
    float* dst = featsT + ((size_t)bt * Nn + n0) * CIN + c0;
    #pragma unroll
    for (int r = 0; r < 16; r++) {
        int n = ty + r * 4;
        dst[(size_t)n * CIN + tx] = tile[tx][n];
    }
}

// ---------------------------------------------------------------------------
// Kernel 4: interpolate -> Xp [BT][256][M] PACKED (hi<<16 | lo) bf16 split.
// ---------------------------------------------------------------------------
__global__ __launch_bounds__(256) void interp_kernel(
    const float* __restrict__ featsT,  // [BT][1024][256]
    const int*   __restrict__ idx,     // [BT][M][3]
    const float* __restrict__ w,       // [BT][M][3]
    unsigned int* __restrict__ Xp)     // [BT][256][M] packed
{
    __shared__ float sX[256][33];
    __shared__ int   sidx[96];
    __shared__ float swgt[96];
    int bt = blockIdx.y;
    int m0 = blockIdx.x * 32;
    int tid = threadIdx.x;
    size_t base = ((size_t)bt * Mm + m0) * 3;
    if (tid < 96)       sidx[tid]      = idx[base + tid];
    else if (tid < 192) swgt[tid - 96] = w[base + tid - 96];
    __syncthreads();

    const float* fb = featsT + (size_t)bt * Nn * CIN + tid;   // c = tid
    #pragma unroll 4
    for (int mm = 0; mm < 32; mm++) {
        int   j0 = sidx[mm * 3 + 0], j1 = sidx[mm * 3 + 1], j2 = sidx[mm * 3 + 2];
        float w0 = swgt[mm * 3 + 0], w1 = swgt[mm * 3 + 1], w2 = swgt[mm * 3 + 2];
        sX[tid][mm] = w0 * fb[(size_t)j0 * CIN]
                    + w1 * fb[(size_t)j1 * CIN]
                    + w2 * fb[(size_t)j2 * CIN];
    }
    __syncthreads();

    unsigned int* xb = Xp + (size_t)bt * CIN * Mm + m0;
    #pragma unroll
    for (int i = 0; i < 8; i++) {
        int row = i * 32 + (tid >> 3);
        int col = (tid & 7) * 4;
        uint4 v;
        v.x = pack_bf(sX[row][col]);
        v.y = pack_bf(sX[row][col + 1]);
        v.z = pack_bf(sX[row][col + 2]);
        v.w = pack_bf(sX[row][col + 3]);
        *(uint4*)&xb[(size_t)row * Mm + col] = v;
    }
}

// ---------------------------------------------------------------------------
// Kernel 5: split-bf16 MFMA GEMM with T14 staging split + fused BN stats.
//   Y[bt][o][m] = sum_c W[o][c] * f(src[c][m]),  f = id or BN1+relu.
//   CONCAT: k<CIN reads packed Xp, k>=CIN reads ofeats fp32 (split in-stage).
//   K-loop: issue loads(k+1) -> MFMA(k) -> barrier -> split/write(k+1) -> barrier.
//   Epilogue: Y write + per-o-row s1/s2 shuffle-reduce + atomicAdd to statsAcc.
// grid: (Mm/128, 2, BT)
// ---------------------------------------------------------------------------
template <int KTOT, bool TRANSFORM, bool CONCAT>
__global__ __launch_bounds__(256) void mfma_gemm_kernel(
    const unsigned short* __restrict__ Whi,  // [256][KTOT] bf16 bits
    const unsigned short* __restrict__ Wlo,
    const unsigned int* __restrict__ Xg,     // packed (CONCAT k<CIN) or fp32 bits
    const float* __restrict__ OF,            // [BT][CORIG][Mm] (CONCAT) or null
    const float* __restrict__ stats,         // [T][KTOT][2] (a,b) or null
    float* __restrict__ Y,                   // [BT][256][Mm]
    float* __restrict__ statsAcc)            // [T][256][2] S1,S2 accumulators
{
    __shared__ unsigned short sAhi[128][40];
    __shared__ unsigned short sAlo[128][40];
    __shared__ unsigned short sBhi[128][40];
    __shared__ unsigned short sBlo[128][40];
    __shared__ float sStats[TRANSFORM ? 2 * KTOT : 2];

    const int tid = threadIdx.x;
    const int bt = blockIdx.z, t = bt & (Tt - 1);
    const int m0 = blockIdx.x * 128, o0 = blockIdx.y * 128;

    // staging roles
    const int mo = tid & 127;    // tile row (o' for A, m' for B)
    const int kh = tid >> 7;     // k-half 0/1 (16 k each) — wave-uniform
    const unsigned int* Xb = Xg + (size_t)bt * (CONCAT ? CIN : KTOT) * Mm + m0 + mo;
    const float* OFb = CONCAT ? (OF + (size_t)bt * CORIG * Mm + m0 + mo) : nullptr;

    // compute roles
    const int lane = tid & 63, wid = tid >> 6;
    const int wo = (wid >> 1) * 64, wm = (wid & 1) * 64;
    const int lr = lane & 15, kb = lane >> 4;

    if (TRANSFORM) {
        for (int i = tid; i < 2 * KTOT; i += 256)
            sStats[i] = stats[t * KTOT * 2 + i];
    }

    f32x4 acc[4][4] = {};
    unsigned int rb[16];
    uint4 ra0, ra1, ra2, ra3;

    auto LOADA = [&](int k0_) {
        const uint4* ph = (const uint4*)&Whi[(size_t)(o0 + mo) * KTOT + k0_ + kh * 16];
        const uint4* pl = (const uint4*)&Wlo[(size_t)(o0 + mo) * KTOT + k0_ + kh * 16];
        ra0 = ph[0]; ra1 = ph[1]; ra2 = pl[0]; ra3 = pl[1];
    };
    auto LOADB = [&](int k0_) {
        const int kg = k0_ + kh * 16;   // wave-uniform; never straddles CIN
        if (CONCAT && kg >= CIN) {
            const float* p = OFb + (size_t)(kg - CIN) * Mm;
            #pragma unroll
            for (int kk = 0; kk < 16; kk++)
                rb[kk] = __float_as_uint(p[(size_t)kk * Mm]);
        } else {
            const unsigned int* p = Xb + (size_t)kg * Mm;
            #pragma unroll
            for (int kk = 0; kk < 16; kk++)
                rb[kk] = p[(size_t)kk * Mm];
        }
    };
    auto STORE = [&](int k0_) {
        const int kg = k0_ + kh * 16;
        *(uint4*)&sAhi[mo][kh * 16]     = ra0;
        *(uint4*)&sAhi[mo][kh * 16 + 8] = ra1;
        *(uint4*)&sAlo[mo][kh * 16]     = ra2;
        *(uint4*)&sAlo[mo][kh * 16 + 8] = ra3;
        s16x8 H0, H1, L0, L1;
        const bool packed = CONCAT && (kg < CIN);
        #pragma unroll
        for (int kk = 0; kk < 8; kk++) {
            unsigned short h, l, h2, l2;
            if (packed) {
                unsigned int p = rb[kk], q = rb[kk + 8];
                h  = (unsigned short)(p >> 16); l  = (unsigned short)(p & 0xFFFFu);
                h2 = (unsigned short)(q >> 16); l2 = (unsigned short)(q & 0xFFFFu);
            } else {
                float v = __uint_as_float(rb[kk]);
                float v2 = __uint_as_float(rb[kk + 8]);
                if (TRANSFORM) {
                    int k = kg + kk;
                    v  = fmaxf(fmaf(sStats[k * 2],        v,  sStats[k * 2 + 1]),  0.0f);
                    v2 = fmaxf(fmaf(sStats[(k + 8) * 2],  v2, sStats[(k + 8) * 2 + 1]), 0.0f);
                }
                split_bf16(v, h, l);
                split_bf16(v2, h2, l2);
            }
            H0[kk] = (short)h;  L0[kk] = (short)l;
            H1[kk] = (short)h2; L1[kk] = (short)l2;
        }
        *(s16x8*)&sBhi[mo][kh * 16]     = H0;
        *(s16x8*)&sBhi[mo][kh * 16 + 8] = H1;
        *(s16x8*)&sBlo[mo][kh * 16]     = L0;
        *(s16x8*)&sBlo[mo][kh * 16 + 8] = L1;
    };

    // prologue: tile 0
    LOADA(0); LOADB(0);
    STORE(0);
    __syncthreads();

    for (int k0 = 0; k0 < KTOT; k0 += 32) {
        const bool more = (k0 + 32) < KTOT;
        if (more) { LOADA(k0 + 32); LOADB(k0 + 32); }   // prefetch under MFMA

        s16x8 ah[4], al[4], bh[4], bl[4];
        #pragma unroll
        for (int f = 0; f < 4; f++) {
            ah[f] = *(const s16x8*)&sAhi[wo + f * 16 + lr][kb * 8];
            al[f] = *(const s16x8*)&sAlo[wo + f * 16 + lr][kb * 8];
            bh[f] = *(const s16x8*)&sBhi[wm + f * 16 + lr][kb * 8];
            bl[f] = *(const s16x8*)&sBlo[wm + f * 16 + lr][kb * 8];
        }
        #pragma unroll
        for (int fo = 0; fo < 4; fo++) {
            #pragma unroll
            for (int fn = 0; fn < 4; fn++) {
                acc[fo][fn] = __builtin_amdgcn_mfma_f32_16x16x32_bf16(ah[fo], bh[fn], acc[fo][fn], 0, 0, 0);
                acc[fo][fn] = __builtin_amdgcn_mfma_f32_16x16x32_bf16(ah[fo], bl[fn], acc[fo][fn], 0, 0, 0);
                acc[fo][fn] = __builtin_amdgcn_mfma_f32_16x16x32_bf16(al[fo], bh[fn], acc[fo][fn], 0, 0, 0);
            }
        }
        __syncthreads();            // all reads of LDS(k0) done
        if (more) {
            STORE(k0 + 32);         // write next tile
            __syncthreads();
        }
    }

    // ---- epilogue: Y write + fused BN partial stats ----
    float* Yb = Y + (size_t)bt * 256 * Mm;
    #pragma unroll
    for (int fo = 0; fo < 4; fo++) {
        int obase = o0 + wo + fo * 16 + kb * 4;
        #pragma unroll
        for (int r = 0; r < 4; r++) {
            float* row = &Yb[(size_t)(obase + r) * Mm + m0 + wm + lr];
            #pragma unroll
            for (int fn = 0; fn < 4; fn++)
                row[fn * 16] = acc[fo][fn][r];
        }
    }
    // per-o-row partial sums over this block's 128 m values (wave covers 64)
    #pragma unroll
    for (int fo = 0; fo < 4; fo++) {
        #pragma unroll
        for (int r = 0; r < 4; r++) {
            float a1 = 0.0f, a2 = 0.0f;
            #pragma unroll
            for (int fn = 0; fn < 4; fn++) {
                float v = acc[fo][fn][r];
                a1 += v;
                a2 += v * v;
            }
            #pragma unroll
            for (int msk = 1; msk < 16; msk <<= 1) {
                a1 += __shfl_xor(a1, msk);
                a2 += __shfl_xor(a2, msk);
            }
            if (lr == 0) {
                int o = o0 + wo + fo * 16 + kb * 4 + r;
                atomicAdd(&statsAcc[(t * 256 + o) * 2 + 0], a1);
                atomicAdd(&statsAcc[(t * 256 + o) * 2 + 1], a2);
            }
        }
    }
}

// ---------------------------------------------------------------------------
// Kernel 6: finalize BN stats in place: (S1,S2) -> (a, b)
// ---------------------------------------------------------------------------
__global__ __launch_bounds__(256) void finalize_stats_kernel(
    float* __restrict__ acc, const float* __restrict__ gamma,
    const float* __restrict__ beta)
{
    int i = blockIdx.x * 256 + threadIdx.x;   // t*256 + o, 1024 total
    int o = i & 255;
    float S1 = acc[i * 2], S2 = acc[i * 2 + 1];
    const float inv = 1.0f / (float)(Bb * Mm);
    float mean = S1 * inv;
    float var  = S2 * inv - mean * mean;
    float a = gamma[o] * rsqrtf(var + EPS_BN);
    acc[i * 2]     = a;
    acc[i * 2 + 1] = beta[o] - mean * a;
}

// ---------------------------------------------------------------------------
// Kernel 7: final BN2 + relu apply -> d_out
// ---------------------------------------------------------------------------
__global__ __launch_bounds__(256) void bn_apply_kernel(
    const float* __restrict__ Y,      // [BT][P][M]
    const float* __restrict__ stats,  // [T][P][2] (a,b)
    float* __restrict__ out)
{
    size_t i4 = (size_t)blockIdx.x * 256 + threadIdx.x;
    size_t r = i4 >> 10;               // (bt*256 + o)
    int o  = (int)(r & 255);
    int bt = (int)(r >> 8);
    int t  = bt & (Tt - 1);
    float a = stats[(t * 256 + o) * 2 + 0];
    float b = stats[(t * 256 + o) * 2 + 1];
    float4 v = *(const float4*)&Y[i4 * 4];
    v.x = fmaxf(fmaf(a, v.x, b), 0.0f);
    v.y = fmaxf(fmaf(a, v.y, b), 0.0f);
    v.z = fmaxf(fmaf(a, v.z, b), 0.0f);
    v.w = fmaxf(fmaf(a, v.w, b), 0.0f);
    *(float4*)&out[i4 * 4] = v;
}

// ---------------------------------------------------------------------------
extern "C" void kernel_launch(void* const* d_in, const int* in_sizes, int n_in,
                              void* d_out, int out_size, void* d_ws, size_t ws_size,
                              hipStream_t stream)
{
    const float* xyzs   = (const float*)d_in[0];
    const float* oxyzs  = (const float*)d_in[1];
    const float* feats  = (const float*)d_in[2];
    const float* ofeats = (const float*)d_in[3];
    const float* W1     = (const float*)d_in[4];
    const float* gamma1 = (const float*)d_in[5];
    const float* beta1  = (const float*)d_in[6];
    const float* W2     = (const float*)d_in[7];
    const float* gamma2 = (const float*)d_in[8];
    const float* beta2  = (const float*)d_in[9];
    float* out = (float*)d_out;

    // workspace layout (bytes)
    char* ws = (char*)d_ws;
    int*            idx_ws = (int*)ws;                          // 1,572,864 B
    float*          w_ws   = (float*)(ws + 1572864);            // 1,572,864 B
    unsigned short* Whi1   = (unsigned short*)(ws + 3145728);   // 196,608 B
    unsigned short* Wlo1   = (unsigned short*)(ws + 3342336);   // 196,608 B
    unsigned short* Whi2   = (unsigned short*)(ws + 3538944);   // 131,072 B
    unsigned short* Wlo2   = (unsigned short*)(ws + 3670016);   // 131,072 B
    float*          sAcc1  = (float*)(ws + 3801088);            // 8,192 B (S1,S2 -> a,b)
    float*          sAcc2  = (float*)(ws + 3809280);            // 8,192 B
    float*          featsT = (float*)(ws + 4194304);            // 33,554,432 B
    unsigned int*   Xp     = (unsigned int*)(ws + 37748736);    // 134,217,728 B (packed)
    float*          Y1     = (float*)(ws + 171966464);          // 134,217,728 B
    float*          Y2     = (float*)Xp;   // Xp dead after GEMM1

    // 1) passthrough output: original_xyzs
    hipMemcpyAsync(out, oxyzs, 393216 * sizeof(float),
                   hipMemcpyDeviceToDevice, stream);

    // 2) weight hi/lo splits + zero stat accumulators (sAcc1,sAcc2 contiguous)
    prep_w_kernel<<<(P1 * CTOT + 255) / 256, 256, 0, stream>>>(W1, Whi1, Wlo1, P1 * CTOT);
    prep_w_kernel<<<(P2 * P1 + 255) / 256, 256, 0, stream>>>(W2, Whi2, Wlo2, P2 * P1);
    zero_stats_kernel<<<16, 256, 0, stream>>>(sAcc1);

    // 3) three_nn
    three_nn_kernel<<<dim3(Mm / 256, BT), 256, 0, stream>>>(xyzs, oxyzs, idx_ws, w_ws);

    // 4) feats transpose + coalesced interp (writes packed hi/lo)
    transpose_feats_kernel<<<dim3(Nn / 64, CIN / 64, BT), 256, 0, stream>>>(feats, featsT);
    interp_kernel<<<dim3(Mm / 32, BT), 256, 0, stream>>>(featsT, idx_ws, w_ws, Xp);

    // 5) GEMM1 (split-bf16 MFMA, zero-copy concat, fused BN1 partial stats)
    mfma_gemm_kernel<CTOT, false, true><<<dim3(Mm / 128, 2, BT), 256, 0, stream>>>(
        Whi1, Wlo1, Xp, ofeats, nullptr, Y1, sAcc1);
    finalize_stats_kernel<<<4, 256, 0, stream>>>(sAcc1, gamma1, beta1);

    // 6) GEMM2 with fused BN1+relu on input, fused BN2 partial stats
    mfma_gemm_kernel<P1, true, false><<<dim3(Mm / 128, 2, BT), 256, 0, stream>>>(
        Whi2, Wlo2, (const unsigned int*)Y1, nullptr, sAcc1, Y2, sAcc2);
    finalize_stats_kernel<<<4, 256, 0, stream>>>(sAcc2, gamma2, beta2);

    // 7) BN2 + relu apply -> out
    bn_apply_kernel<<<(BT * 256 * Mm / 4) / 256, 256, 0, stream>>>(
        Y2, sAcc2, out + 393216);
}

// Round 8
// 708.767 us; speedup vs baseline: 1.0700x; 1.0700x over previous
//
#include <hip/hip_runtime.h>
#include <hip/hip_bf16.h>

// Problem constants
#define Bb 8
#define Tt 4
#define Nn 1024
#define Mm 4096
#define BT 32         // B*T
#define CIN 256
#define CORIG 128
#define CTOT 384      // CIN + CORIG
#define P1 256
#define P2 256
#define EPS_D 1e-8f
#define EPS_BN 1e-5f

typedef __attribute__((ext_vector_type(4))) float f32x4;
typedef __attribute__((ext_vector_type(8))) short s16x8;

// ---- bf16 split helpers (RTNE; fp32-grade when both pieces used) ----
__device__ __forceinline__ unsigned short f2bf(float f) {
    unsigned int u = __float_as_uint(f);
    unsigned int r = (u + 0x7FFFu + ((u >> 16) & 1u)) >> 16;
    return (unsigned short)r;
}
__device__ __forceinline__ float bf2f(unsigned short b) {
    return __uint_as_float((unsigned int)b << 16);
}
__device__ __forceinline__ void split_bf16(float f, unsigned short& h, unsigned short& l) {
    h = f2bf(f);
    l = f2bf(f - bf2f(h));
}
__device__ __forceinline__ unsigned int pack_bf(float f) {
    unsigned short h, l;
    split_bf16(f, h, l);
    return ((unsigned int)h << 16) | (unsigned int)l;
}

// ---------------------------------------------------------------------------
// Kernel 1: split W[o][k] fp32 -> bf16 hi/lo pair (same [o][k] layout)
// ---------------------------------------------------------------------------
__global__ __launch_bounds__(256) void prep_w_kernel(
    const float* __restrict__ W, unsigned short* __restrict__ hi,
    unsigned short* __restrict__ lo, int total)
{
    int i = blockIdx.x * 256 + threadIdx.x;
    if (i < total) {
        unsigned short h, l;
        split_bf16(W[i], h, l);
        hi[i] = h; lo[i] = l;
    }
}

// ---------------------------------------------------------------------------
// Kernel 1b: zero the BN-stat accumulators (ws is poisoned before each launch)
// ---------------------------------------------------------------------------
__global__ __launch_bounds__(256) void zero_stats_kernel(float* __restrict__ p)
{
    p[blockIdx.x * 256 + threadIdx.x] = 0.0f;
}

// ---------------------------------------------------------------------------
// Kernel 2: three_nn — per query point find 3 nearest (squared dist), weights
// ---------------------------------------------------------------------------
__global__ __launch_bounds__(256) void three_nn_kernel(
    const float* __restrict__ xyzs,   // [BT][N][3]
    const float* __restrict__ oxyzs,  // [BT][M][3]
    int*   __restrict__ idx_out,      // [BT][M][3]
    float* __restrict__ w_out)        // [BT][M][3]
{
    __shared__ float sx[Nn], sy[Nn], sz[Nn];
    int bt = blockIdx.y;
    const float* base = xyzs + (size_t)bt * Nn * 3;
    for (int i = threadIdx.x; i < Nn; i += 256) {
        sx[i] = base[i * 3 + 0];
        sy[i] = base[i * 3 + 1];
        sz[i] = base[i * 3 + 2];
    }
    __syncthreads();

    int m = blockIdx.x * 256 + threadIdx.x;
    size_t q = ((size_t)bt * Mm + m) * 3;
    float qx = oxyzs[q + 0], qy = oxyzs[q + 1], qz = oxyzs[q + 2];

    float d0 = 3.4e38f, d1 = 3.4e38f, d2v = 3.4e38f;
    int   i0 = 0, i1 = 0, i2 = 0;
    #pragma unroll 4
    for (int n = 0; n < Nn; n++) {
        float dx = qx - sx[n], dy = qy - sy[n], dz = qz - sz[n];
        float d = dx * dx + dy * dy + dz * dz;
        bool lt0 = d < d0, lt1 = d < d1, lt2 = d < d2v;
        i2  = lt1 ? i1 : (lt2 ? n : i2);
        d2v = lt1 ? d1 : (lt2 ? d : d2v);
        i1  = lt0 ? i0 : (lt1 ? n : i1);
        d1  = lt0 ? d0 : (lt1 ? d : d1);
        i0  = lt0 ? n : i0;
        d0  = lt0 ? d : d0;
    }
    float w0 = 1.0f / (d0 + EPS_D);
    float w1 = 1.0f / (d1 + EPS_D);
    float w2 = 1.0f / (d2v + EPS_D);
    float inv = 1.0f / (w0 + w1 + w2);
    idx_out[q + 0] = i0; idx_out[q + 1] = i1; idx_out[q + 2] = i2;
    w_out[q + 0] = w0 * inv; w_out[q + 1] = w1 * inv; w_out[q + 2] = w2 * inv;
}

// ---------------------------------------------------------------------------
// Kernel 3: transpose feats [BT][256][1024] -> featsT [BT][1024][256]
// ---------------------------------------------------------------------------
__global__ __launch_bounds__(256) void transpose_feats_kernel(
    const float* __restrict__ feats, float* __restrict__ featsT)
{
    __shared__ float tile[64][65];
    int bt = blockIdx.z;
    int n0 = blockIdx.x * 64;
    int c0 = blockIdx.y * 64;
    int tx = threadIdx.x & 63;
    int ty = threadIdx.x >> 6;
    const float* src = feats + ((size_t)bt * CIN + c0) * Nn + n0;
    #pragma unroll
    for (int r = 0; r < 16; r++) {
        int c = ty + r * 4;
        tile[c][tx] = src[(size_t)c * Nn + tx];
    }
    __syncthreads();
    float* dst = featsT + ((size_t)bt * Nn + n0) * CIN + c0;
    #pragma unroll
    for (int r = 0; r < 16; r++) {
        int n = ty + r * 4;
        dst[(size_t)n * CIN + tx] = tile[tx][n];
    }
}

// ---------------------------------------------------------------------------
// Kernel 4: interpolate -> Xp [BT][256][M] PACKED (hi<<16 | lo) bf16 split.
// ---------------------------------------------------------------------------
__global__ __launch_bounds__(256) void interp_kernel(
    const float* __restrict__ featsT,  // [BT][1024][256]
    const int*   __restrict__ idx,     // [BT][M][3]
    const float* __restrict__ w,       // [BT][M][3]
    unsigned int* __restrict__ Xp)     // [BT][256][M] packed
{
    __shared__ float sX[256][33];
    __shared__ int   sidx[96];
    __shared__ float swgt[96];
    int bt = blockIdx.y;
    int m0 = blockIdx.x * 32;
    int tid = threadIdx.x;
    size_t base = ((size_t)bt * Mm + m0) * 3;
    if (tid < 96)       sidx[tid]      = idx[base + tid];
    else if (tid < 192) swgt[tid - 96] = w[base + tid - 96];
    __syncthreads();

    const float* fb = featsT + (size_t)bt * Nn * CIN + tid;   // c = tid
    #pragma unroll 4
    for (int mm = 0; mm < 32; mm++) {
        int   j0 = sidx[mm * 3 + 0], j1 = sidx[mm * 3 + 1], j2 = sidx[mm * 3 + 2];
        float w0 = swgt[mm * 3 + 0], w1 = swgt[mm * 3 + 1], w2 = swgt[mm * 3 + 2];
        sX[tid][mm] = w0 * fb[(size_t)j0 * CIN]
                    + w1 * fb[(size_t)j1 * CIN]
                    + w2 * fb[(size_t)j2 * CIN];
    }
    __syncthreads();

    unsigned int* xb = Xp + (size_t)bt * CIN * Mm + m0;
    #pragma unroll
    for (int i = 0; i < 8; i++) {
        int row = i * 32 + (tid >> 3);
        int col = (tid & 7) * 4;
        uint4 v;
        v.x = pack_bf(sX[row][col]);
        v.y = pack_bf(sX[row][col + 1]);
        v.z = pack_bf(sX[row][col + 2]);
        v.w = pack_bf(sX[row][col + 3]);
        *(uint4*)&xb[(size_t)row * Mm + col] = v;
    }
}

// ---------------------------------------------------------------------------
// Kernel 5: split-bf16 MFMA GEMM (round-5 loop shape) + fused BN stats.
//   Y[bt][o][m] = sum_c W[o][c] * f(src[c][m]),  f = id or BN1+relu.
//   CONCAT: k<CIN reads packed Xp, k>=CIN reads ofeats fp32 (split in-stage).
//   K-loop: STORE(k) -> barrier -> [issue LOAD(k+1), frag reads, MFMA(k)]
//           -> barrier.  (Prefetch issued after the barrier; compiler drains
//           vmcnt before s_barrier, so loads must not cross one.)
//   Epilogue: Y write + per-o-row s1/s2 shuffle-reduce + atomicAdd.
// grid: (Mm/128, 2, BT)
// ---------------------------------------------------------------------------
template <int KTOT, bool TRANSFORM, bool CONCAT>
__global__ __launch_bounds__(256) void mfma_gemm_kernel(
    const unsigned short* __restrict__ Whi,  // [256][KTOT] bf16 bits
    const unsigned short* __restrict__ Wlo,
    const unsigned int* __restrict__ Xg,     // packed (CONCAT k<CIN) or fp32 bits
    const float* __restrict__ OF,            // [BT][CORIG][Mm] (CONCAT) or null
    const float* __restrict__ stats,         // [T][KTOT][2] (a,b) or null
    float* __restrict__ Y,                   // [BT][256][Mm]
    float* __restrict__ statsAcc)            // [T][256][2] S1,S2 accumulators
{
    __shared__ unsigned short sAhi[128][40];
    __shared__ unsigned short sAlo[128][40];
    __shared__ unsigned short sBhi[128][40];
    __shared__ unsigned short sBlo[128][40];
    __shared__ float sStats[TRANSFORM ? 2 * KTOT : 2];

    const int tid = threadIdx.x;
    const int bt = blockIdx.z, t = bt & (Tt - 1);
    const int m0 = blockIdx.x * 128, o0 = blockIdx.y * 128;

    // staging roles
    const int mo = tid & 127;    // tile row (o' for A, m' for B)
    const int kh = tid >> 7;     // k-half 0/1 (16 k each) — wave-uniform
    const unsigned int* Xb = Xg + (size_t)bt * (CONCAT ? CIN : KTOT) * Mm + m0 + mo;
    const float* OFb = CONCAT ? (OF + (size_t)bt * CORIG * Mm + m0 + mo) : nullptr;

    // compute roles
    const int lane = tid & 63, wid = tid >> 6;
    const int wo = (wid >> 1) * 64, wm = (wid & 1) * 64;
    const int lr = lane & 15, kb = lane >> 4;

    if (TRANSFORM) {
        for (int i = tid; i < 2 * KTOT; i += 256)
            sStats[i] = stats[t * KTOT * 2 + i];
        __syncthreads();   // cross-wave visibility before first STORE uses it
    }

    f32x4 acc[4][4] = {};
    unsigned int rb[16];
    uint4 ra0, ra1, ra2, ra3;

    auto LOADA = [&](int k0_) {
        const uint4* ph = (const uint4*)&Whi[(size_t)(o0 + mo) * KTOT + k0_ + kh * 16];
        const uint4* pl = (const uint4*)&Wlo[(size_t)(o0 + mo) * KTOT + k0_ + kh * 16];
        ra0 = ph[0]; ra1 = ph[1]; ra2 = pl[0]; ra3 = pl[1];
    };
    auto LOADB = [&](int k0_) {
        const int kg = k0_ + kh * 16;   // wave-uniform; never straddles CIN
        if (CONCAT && kg >= CIN) {
            const float* p = OFb + (size_t)(kg - CIN) * Mm;
            #pragma unroll
            for (int kk = 0; kk < 16; kk++)
                rb[kk] = __float_as_uint(p[(size_t)kk * Mm]);
        } else {
            const unsigned int* p = Xb + (size_t)kg * Mm;
            #pragma unroll
            for (int kk = 0; kk < 16; kk++)
                rb[kk] = p[(size_t)kk * Mm];
        }
    };
    auto STORE = [&](int k0_) {
        const int kg = k0_ + kh * 16;
        *(uint4*)&sAhi[mo][kh * 16]     = ra0;
        *(uint4*)&sAhi[mo][kh * 16 + 8] = ra1;
        *(uint4*)&sAlo[mo][kh * 16]     = ra2;
        *(uint4*)&sAlo[mo][kh * 16 + 8] = ra3;
        s16x8 H0, H1, L0, L1;
        const bool packed = CONCAT && (kg < CIN);
        #pragma unroll
        for (int kk = 0; kk < 8; kk++) {
            unsigned short h, l, h2, l2;
            if (packed) {
                unsigned int p = rb[kk], q = rb[kk + 8];
                h  = (unsigned short)(p >> 16); l  = (unsigned short)(p & 0xFFFFu);
                h2 = (unsigned short)(q >> 16); l2 = (unsigned short)(q & 0xFFFFu);
            } else {
                float v = __uint_as_float(rb[kk]);
                float v2 = __uint_as_float(rb[kk + 8]);
                if (TRANSFORM) {
                    int k = kg + kk;
                    v  = fmaxf(fmaf(sStats[k * 2],        v,  sStats[k * 2 + 1]),  0.0f);
                    v2 = fmaxf(fmaf(sStats[(k + 8) * 2],  v2, sStats[(k + 8) * 2 + 1]), 0.0f);
                }
                split_bf16(v, h, l);
                split_bf16(v2, h2, l2);
            }
            H0[kk] = (short)h;  L0[kk] = (short)l;
            H1[kk] = (short)h2; L1[kk] = (short)l2;
        }
        *(s16x8*)&sBhi[mo][kh * 16]     = H0;
        *(s16x8*)&sBhi[mo][kh * 16 + 8] = H1;
        *(s16x8*)&sBlo[mo][kh * 16]     = L0;
        *(s16x8*)&sBlo[mo][kh * 16 + 8] = L1;
    };

    // prologue: load k-tile 0 into registers
    LOADA(0); LOADB(0);

    for (int k0 = 0; k0 < KTOT; k0 += 32) {
        STORE(k0);
        __syncthreads();
        if (k0 + 32 < KTOT) { LOADA(k0 + 32); LOADB(k0 + 32); }  // issue under MFMA

        s16x8 ah[4], al[4], bh[4], bl[4];
        #pragma unroll
        for (int f = 0; f < 4; f++) {
            ah[f] = *(const s16x8*)&sAhi[wo + f * 16 + lr][kb * 8];
            al[f] = *(const s16x8*)&sAlo[wo + f * 16 + lr][kb * 8];
            bh[f] = *(const s16x8*)&sBhi[wm + f * 16 + lr][kb * 8];
            bl[f] = *(const s16x8*)&sBlo[wm + f * 16 + lr][kb * 8];
        }
        #pragma unroll
        for (int fo = 0; fo < 4; fo++) {
            #pragma unroll
            for (int fn = 0; fn < 4; fn++) {
                acc[fo][fn] = __builtin_amdgcn_mfma_f32_16x16x32_bf16(ah[fo], bh[fn], acc[fo][fn], 0, 0, 0);
                acc[fo][fn] = __builtin_amdgcn_mfma_f32_16x16x32_bf16(ah[fo], bl[fn], acc[fo][fn], 0, 0, 0);
                acc[fo][fn] = __builtin_amdgcn_mfma_f32_16x16x32_bf16(al[fo], bh[fn], acc[fo][fn], 0, 0, 0);
            }
        }
        __syncthreads();
    }

    // ---- epilogue: Y write + fused BN partial stats ----
    float* Yb = Y + (size_t)bt * 256 * Mm;
    #pragma unroll
    for (int fo = 0; fo < 4; fo++) {
        int obase = o0 + wo + fo * 16 + kb * 4;
        #pragma unroll
        for (int r = 0; r < 4; r++) {
            float* row = &Yb[(size_t)(obase + r) * Mm + m0 + wm + lr];
            #pragma unroll
            for (int fn = 0; fn < 4; fn++)
                row[fn * 16] = acc[fo][fn][r];
        }
    }
    // per-o-row partial sums over this block's 64 m values per wave
    #pragma unroll
    for (int fo = 0; fo < 4; fo++) {
        #pragma unroll
        for (int r = 0; r < 4; r++) {
            float a1 = 0.0f, a2 = 0.0f;
            #pragma unroll
            for (int fn = 0; fn < 4; fn++) {
                float v = acc[fo][fn][r];
                a1 += v;
                a2 += v * v;
            }
            #pragma unroll
            for (int msk = 1; msk < 16; msk <<= 1) {
                a1 += __shfl_xor(a1, msk);
                a2 += __shfl_xor(a2, msk);
            }
            if (lr == 0) {
                int o = o0 + wo + fo * 16 + kb * 4 + r;
                atomicAdd(&statsAcc[(t * 256 + o) * 2 + 0], a1);
                atomicAdd(&statsAcc[(t * 256 + o) * 2 + 1], a2);
            }
        }
    }
}

// ---------------------------------------------------------------------------
// Kernel 6: finalize BN stats in place: (S1,S2) -> (a, b)
// ---------------------------------------------------------------------------
__global__ __launch_bounds__(256) void finalize_stats_kernel(
    float* __restrict__ acc, const float* __restrict__ gamma,
    const float* __restrict__ beta)
{
    int i = blockIdx.x * 256 + threadIdx.x;   // t*256 + o, 1024 total
    int o = i & 255;
    float S1 = acc[i * 2], S2 = acc[i * 2 + 1];
    const float inv = 1.0f / (float)(Bb * Mm);
    float mean = S1 * inv;
    float var  = S2 * inv - mean * mean;
    float a = gamma[o] * rsqrtf(var + EPS_BN);
    acc[i * 2]     = a;
    acc[i * 2 + 1] = beta[o] - mean * a;
}

// ---------------------------------------------------------------------------
// Kernel 7: final BN2 + relu apply -> d_out
// ---------------------------------------------------------------------------
__global__ __launch_bounds__(256) void bn_apply_kernel(
    const float* __restrict__ Y,      // [BT][P][M]
    const float* __restrict__ stats,  // [T][P][2] (a,b)
    float* __restrict__ out)
{
    size_t i4 = (size_t)blockIdx.x * 256 + threadIdx.x;
    size_t r = i4 >> 10;               // (bt*256 + o)
    int o  = (int)(r & 255);
    int bt = (int)(r >> 8);
    int t  = bt & (Tt - 1);
    float a = stats[(t * 256 + o) * 2 + 0];
    float b = stats[(t * 256 + o) * 2 + 1];
    float4 v = *(const float4*)&Y[i4 * 4];
    v.x = fmaxf(fmaf(a, v.x, b), 0.0f);
    v.y = fmaxf(fmaf(a, v.y, b), 0.0f);
    v.z = fmaxf(fmaf(a, v.z, b), 0.0f);
    v.w = fmaxf(fmaf(a, v.w, b), 0.0f);
    *(float4*)&out[i4 * 4] = v;
}

// ---------------------------------------------------------------------------
extern "C" void kernel_launch(void* const* d_in, const int* in_sizes, int n_in,
                              void* d_out, int out_size, void* d_ws, size_t ws_size,
                              hipStream_t stream)
{
    const float* xyzs   = (const float*)d_in[0];
    const float* oxyzs  = (const float*)d_in[1];
    const float* feats  = (const float*)d_in[2];
    const float* ofeats = (const float*)d_in[3];
    const float* W1     = (const float*)d_in[4];
    const float* gamma1 = (const float*)d_in[5];
    const float* beta1  = (const float*)d_in[6];
    const float* W2     = (const float*)d_in[7];
    const float* gamma2 = (const float*)d_in[8];
    const float* beta2  = (const float*)d_in[9];
    float* out = (float*)d_out;

    // workspace layout (bytes)
    char* ws = (char*)d_ws;
    int*            idx_ws = (int*)ws;                          // 1,572,864 B
    float*          w_ws   = (float*)(ws + 1572864);            // 1,572,864 B
    unsigned short* Whi1   = (unsigned short*)(ws + 3145728);   // 196,608 B
    unsigned short* Wlo1   = (unsigned short*)(ws + 3342336);   // 196,608 B
    unsigned short* Whi2   = (unsigned short*)(ws + 3538944);   // 131,072 B
    unsigned short* Wlo2   = (unsigned short*)(ws + 3670016);   // 131,072 B
    float*          sAcc1  = (float*)(ws + 3801088);            // 8,192 B (S1,S2 -> a,b)
    float*          sAcc2  = (float*)(ws + 3809280);            // 8,192 B
    float*          featsT = (float*)(ws + 4194304);            // 33,554,432 B
    unsigned int*   Xp     = (unsigned int*)(ws + 37748736);    // 134,217,728 B (packed)
    float*          Y1     = (float*)(ws + 171966464);          // 134,217,728 B
    float*          Y2     = (float*)Xp;   // Xp dead after GEMM1

    // 1) passthrough output: original_xyzs
    hipMemcpyAsync(out, oxyzs, 393216 * sizeof(float),
                   hipMemcpyDeviceToDevice, stream);

    // 2) weight hi/lo splits + zero stat accumulators (sAcc1,sAcc2 contiguous)
    prep_w_kernel<<<(P1 * CTOT + 255) / 256, 256, 0, stream>>>(W1, Whi1, Wlo1, P1 * CTOT);
    prep_w_kernel<<<(P2 * P1 + 255) / 256, 256, 0, stream>>>(W2, Whi2, Wlo2, P2 * P1);
    zero_stats_kernel<<<16, 256, 0, stream>>>(sAcc1);

    // 3) three_nn
    three_nn_kernel<<<dim3(Mm / 256, BT), 256, 0, stream>>>(xyzs, oxyzs, idx_ws, w_ws);

    // 4) feats transpose + coalesced interp (writes packed hi/lo)
    transpose_feats_kernel<<<dim3(Nn / 64, CIN / 64, BT), 256, 0, stream>>>(feats, featsT);
    interp_kernel<<<dim3(Mm / 32, BT), 256, 0, stream>>>(featsT, idx_ws, w_ws, Xp);

    // 5) GEMM1 (split-bf16 MFMA, zero-copy concat, fused BN1 partial stats)
    mfma_gemm_kernel<CTOT, false, true><<<dim3(Mm / 128, 2, BT), 256, 0, stream>>>(
        Whi1, Wlo1, Xp, ofeats, nullptr, Y1, sAcc1);
    finalize_stats_kernel<<<4, 256, 0, stream>>>(sAcc1, gamma1, beta1);

    // 6) GEMM2 with fused BN1+relu on input, fused BN2 partial stats
    mfma_gemm_kernel<P1, true, false><<<dim3(Mm / 128, 2, BT), 256, 0, stream>>>(
        Whi2, Wlo2, (const unsigned int*)Y1, nullptr, sAcc1, Y2, sAcc2);
    finalize_stats_kernel<<<4, 256, 0, stream>>>(sAcc2, gamma2, beta2);

    // 7) BN2 + relu apply -> out
    bn_apply_kernel<<<(BT * 256 * Mm / 4) / 256, 256, 0, stream>>>(
        Y2, sAcc2, out + 393216);
}